// Round 3
// baseline (2413.691 us; speedup 1.0000x reference)
//
#include <hip/hip_runtime.h>
#include <math.h>

#define NATOM 10000
#define NEDGE 320000
#define HDIM  128
#define NHEAD 8

typedef short  v8s  __attribute__((ext_vector_type(8)));
typedef float  v4f  __attribute__((ext_vector_type(4)));

__device__ __forceinline__ float silu_f(float x) {
    return x / (1.0f + expf(-x));
}

// f32 -> bf16 (RNE) as raw short; and back
__device__ __forceinline__ short f2bf(float x) {
    union { float f; unsigned u; } c; c.f = x;
    unsigned r = (c.u + 0x7FFF + ((c.u >> 16) & 1)) >> 16;
    return (short)r;
}
__device__ __forceinline__ float bf2f(short h) {
    union { unsigned u; float f; } c; c.u = ((unsigned)(unsigned short)h) << 16;
    return c.f;
}

// ---------------------------------------------------------------- zero (float4)
__global__ __launch_bounds__(256) void k_zero4(float4* __restrict__ p, int n4) {
    int i = blockIdx.x * 256 + threadIdx.x;
    if (i < n4) p[i] = float4{0.f, 0.f, 0.f, 0.f};
}

// ---------------------------------------------------------------- weight prep: split bf16 + transpose to [N=256][K=128]
// mat 0: [Wdk|Wdv], mat 1: Ws, mat 2: Wf
__global__ __launch_bounds__(128) void k_prep(
    const float* __restrict__ Wdk, const float* __restrict__ Wdv,
    const float* __restrict__ Ws,  const float* __restrict__ Wf,
    short* __restrict__ WmsgH, short* __restrict__ WmsgL,
    short* __restrict__ WstH,  short* __restrict__ WstL,
    short* __restrict__ WftH,  short* __restrict__ WftL)
{
    int b = blockIdx.x;            // 0..767
    int mat = b >> 8, n = b & 255, k = threadIdx.x;
    float x;
    if (mat == 0) x = (n < HDIM) ? Wdk[k * HDIM + n] : Wdv[k * HDIM + (n - HDIM)];
    else if (mat == 1) x = Ws[k * 256 + n];
    else x = Wf[k * 256 + n];
    short h = f2bf(x);
    short l = f2bf(x - bf2f(h));
    short* H = (mat == 0) ? WmsgH : (mat == 1) ? WstH : WftH;
    short* L = (mat == 0) ? WmsgL : (mat == 1) ? WstL : WftL;
    H[n * HDIM + k] = h;
    L[n * HDIM + k] = l;
}

// ---------------------------------------------------------------- q,k,v = x@W + b  (8 nodes/block)
__global__ __launch_bounds__(256) void k_node_qkv(
    const float* __restrict__ x,
    const float* __restrict__ Wq, const float* __restrict__ bq,
    const float* __restrict__ Wk, const float* __restrict__ bk,
    const float* __restrict__ Wv, const float* __restrict__ bv,
    float* __restrict__ q, float* __restrict__ k, float* __restrict__ v)
{
    __shared__ float xs[8 * HDIM];
    int base = blockIdx.x * 8;
    reinterpret_cast<float4*>(xs)[threadIdx.x] =
        reinterpret_cast<const float4*>(x + (size_t)base * HDIM)[threadIdx.x];
    __syncthreads();
    int h = threadIdx.x & 127, half = threadIdx.x >> 7;
    float aq[4], ak[4], av[4];
#pragma unroll
    for (int i = 0; i < 4; ++i) { aq[i] = bq[h]; ak[i] = bk[h]; av[i] = bv[h]; }
    for (int kk = 0; kk < HDIM; ++kk) {
        float wq = Wq[kk * HDIM + h], wk = Wk[kk * HDIM + h], wv = Wv[kk * HDIM + h];
#pragma unroll
        for (int i = 0; i < 4; ++i) {
            float xv = xs[(half + 2 * i) * HDIM + kk];
            aq[i] = fmaf(xv, wq, aq[i]);
            ak[i] = fmaf(xv, wk, ak[i]);
            av[i] = fmaf(xv, wv, av[i]);
        }
    }
#pragma unroll
    for (int i = 0; i < 4; ++i) {
        int node = base + half + 2 * i;
        q[(size_t)node * HDIM + h] = aq[i];
        k[(size_t)node * HDIM + h] = ak[i];
        v[(size_t)node * HDIM + h] = av[i];
    }
}

// ---------------------------------------------------------------- vec-side node GEMMs
__global__ __launch_bounds__(256) void k_node_vec(
    const float* __restrict__ vec,
    const float* __restrict__ Wvec,
    const float* __restrict__ Wwtrg, const float* __restrict__ Wwsrc,
    const float* __restrict__ Wttrg, const float* __restrict__ Wtsrc,
    float* __restrict__ vecdot, float* __restrict__ vec3o,
    float* __restrict__ vwt, float* __restrict__ vws,
    float* __restrict__ vtt, float* __restrict__ vts)
{
    __shared__ float vs[8 * 3 * HDIM];
    int base = blockIdx.x * 8;
    {
        const float4* vg = reinterpret_cast<const float4*>(vec + (size_t)base * 3 * HDIM);
        float4* vs4 = reinterpret_cast<float4*>(vs);
        for (int t = threadIdx.x; t < 768; t += 256) vs4[t] = vg[t];
    }
    __syncthreads();
    int h = threadIdx.x & 127, half = threadIdx.x >> 7;
    float vdot[4] = {0.f, 0.f, 0.f, 0.f};
    for (int s = 0; s < 3; ++s) {
        float a1[4] = {0,0,0,0}, a2[4] = {0,0,0,0}, a3[4] = {0,0,0,0};
        float awt[4] = {0,0,0,0}, aws[4] = {0,0,0,0}, att[4] = {0,0,0,0}, ats[4] = {0,0,0,0};
        for (int kk = 0; kk < HDIM; ++kk) {
            float w1 = Wvec[kk * 384 + h];
            float w2 = Wvec[kk * 384 + HDIM + h];
            float w3 = Wvec[kk * 384 + 2 * HDIM + h];
            float wwt = Wwtrg[kk * HDIM + h];
            float wws = Wwsrc[kk * HDIM + h];
            float wtt = Wttrg[kk * HDIM + h];
            float wts = Wtsrc[kk * HDIM + h];
#pragma unroll
            for (int i = 0; i < 4; ++i) {
                float vv = vs[((half + 2 * i) * 3 + s) * HDIM + kk];
                a1[i]  = fmaf(vv, w1, a1[i]);
                a2[i]  = fmaf(vv, w2, a2[i]);
                a3[i]  = fmaf(vv, w3, a3[i]);
                awt[i] = fmaf(vv, wwt, awt[i]);
                aws[i] = fmaf(vv, wws, aws[i]);
                att[i] = fmaf(vv, wtt, att[i]);
                ats[i] = fmaf(vv, wts, ats[i]);
            }
        }
#pragma unroll
        for (int i = 0; i < 4; ++i) {
            int node = base + half + 2 * i;
            size_t ob = ((size_t)node * 3 + s) * HDIM + h;
            vdot[i] += a1[i] * a2[i];
            vec3o[ob] = a3[i];
            vwt[ob] = awt[i];
            vws[ob] = aws[i];
            vtt[ob] = att[i];
            vts[ob] = ats[i];
        }
    }
#pragma unroll
    for (int i = 0; i < 4; ++i)
        vecdot[(size_t)(base + half + 2 * i) * HDIM + h] = vdot[i];
}

// ---------------------------------------------------------------- split-bf16 MFMA GEMM helper
// A (LDS, 272B-stride rows) [64 x 128] hi/lo; B (global, [N][K] bf16) hi/lo.
// Each wave computes 4 mtiles x 4 ntiles (cols given by colbase[]).
__device__ __forceinline__ void gemm_split(
    const short* asHp, const short* asLp,
    const short* __restrict__ WH, const short* __restrict__ WL,
    const int* colbase, int n16, int q8, v4f acc[4][4])
{
#pragma unroll
    for (int kc = 0; kc < 4; ++kc) {
        v8s aH[4], aL[4];
#pragma unroll
        for (int mt = 0; mt < 4; ++mt) {
            int off = (mt * 16 + n16) * 136 + kc * 32 + q8 * 8;
            aH[mt] = *reinterpret_cast<const v8s*>(asHp + off);
            aL[mt] = *reinterpret_cast<const v8s*>(asLp + off);
        }
#pragma unroll
        for (int nt = 0; nt < 4; ++nt) {
            size_t woff = (size_t)(colbase[nt] + n16) * HDIM + kc * 32 + q8 * 8;
            v8s bH = *reinterpret_cast<const v8s*>(WH + woff);
            v8s bL = *reinterpret_cast<const v8s*>(WL + woff);
#pragma unroll
            for (int mt = 0; mt < 4; ++mt) {
                acc[mt][nt] = __builtin_amdgcn_mfma_f32_16x16x32_bf16(aH[mt], bL, acc[mt][nt], 0, 0, 0);
                acc[mt][nt] = __builtin_amdgcn_mfma_f32_16x16x32_bf16(aL[mt], bH, acc[mt][nt], 0, 0, 0);
                acc[mt][nt] = __builtin_amdgcn_mfma_f32_16x16x32_bf16(aH[mt], bH, acc[mt][nt], 0, 0, 0);
            }
        }
    }
}

// ---------------------------------------------------------------- mega edge kernel
// Per 64-edge block (256 thr = 4 waves):
//  stage: f_ij tile -> LDS split bf16
//  P6: df GEMM (f_ij @ Wf) + rejection epilogue -> df_ij
//  P1: [dk|dv] GEMM (f_ij @ [Wdk|Wdv])
//  P2: attn (in-register shfl reduce)   P3: vj -> xagg atomics + LDS split bf16
//  P4: [s1|s2] GEMM (vj @ Ws)           P5: vec_msg scatter -> dvec atomics
__global__ __launch_bounds__(256) void k_edge_mega(
    const float* __restrict__ fij, const int* __restrict__ eidx,
    const float* __restrict__ rij, const float* __restrict__ dij,
    const float* __restrict__ q, const float* __restrict__ k, const float* __restrict__ v,
    const float* __restrict__ vec,
    const short* __restrict__ WmsgH, const short* __restrict__ WmsgL,
    const short* __restrict__ WstH,  const short* __restrict__ WstL,
    const short* __restrict__ WftH,  const short* __restrict__ WftL,
    const float* __restrict__ bdk, const float* __restrict__ bdv,
    const float* __restrict__ bs,  const float* __restrict__ bfb,
    const float* __restrict__ vwt, const float* __restrict__ vws,
    const float* __restrict__ vtt, const float* __restrict__ vts,
    float* __restrict__ xagg, float* __restrict__ dvec, float* __restrict__ dfo)
{
    __shared__ short asH[64 * 136];   // A tile hi (row stride 136 shorts = 272B)
    __shared__ short asL[64 * 136];   // A tile lo
    __shared__ int   srcS[64], dstS[64];
    __shared__ float rcutS[64], d0S[64], d1S[64], d2S[64];

    int e0 = blockIdx.x * 64;
    if (threadIdx.x < 64) {
        int t = threadIdx.x;
        srcS[t] = eidx[e0 + t];
        dstS[t] = eidx[NEDGE + e0 + t];
        float r = rij[e0 + t];
        rcutS[t] = (r < 5.0f) ? 0.5f * (cosf(r * 0.6283185307179586f) + 1.0f) : 0.0f;
        d0S[t] = dij[(size_t)(e0 + t) * 3 + 0];
        d1S[t] = dij[(size_t)(e0 + t) * 3 + 1];
        d2S[t] = dij[(size_t)(e0 + t) * 3 + 2];
    }

    // ---- stage f_ij tile -> split bf16 LDS
    {
        int m  = threadIdx.x >> 2;          // row 0..63
        int q4 = threadIdx.x & 3;           // quarter of row
        const float4* src = reinterpret_cast<const float4*>(fij + (size_t)(e0 + m) * HDIM + q4 * 32);
        short* hp = &asH[m * 136 + q4 * 32];
        short* lp = &asL[m * 136 + q4 * 32];
#pragma unroll
        for (int c8 = 0; c8 < 4; ++c8) {
            float4 x0 = src[c8 * 2], x1 = src[c8 * 2 + 1];
            float xs[8] = {x0.x, x0.y, x0.z, x0.w, x1.x, x1.y, x1.z, x1.w};
            v8s hv, lv;
#pragma unroll
            for (int j = 0; j < 8; ++j) {
                short h = f2bf(xs[j]);
                hv[j] = h;
                lv[j] = f2bf(xs[j] - bf2f(h));
            }
            *reinterpret_cast<v8s*>(hp + c8 * 8) = hv;
            *reinterpret_cast<v8s*>(lp + c8 * 8) = lv;
        }
    }
    __syncthreads();

    int lane = threadIdx.x & 63;
    int wv   = threadIdx.x >> 6;
    int n16  = lane & 15;
    int q8   = lane >> 4;
    int colbase[4] = {wv * 32, wv * 32 + 16, 128 + wv * 32, 128 + wv * 32 + 16};

    v4f acc[4][4];

    // ================= P6: df GEMM + rejection epilogue =================
#pragma unroll
    for (int mt = 0; mt < 4; ++mt)
#pragma unroll
        for (int nt = 0; nt < 4; ++nt) acc[mt][nt] = v4f{0.f, 0.f, 0.f, 0.f};
    gemm_split(asH, asL, WftH, WftL, colbase, n16, q8, acc);

#pragma unroll
    for (int nt2 = 0; nt2 < 2; ++nt2) {
        int c1 = colbase[nt2] + n16;
        float bf1 = bfb[c1], bf2 = bfb[HDIM + c1];
#pragma unroll
        for (int mt = 0; mt < 4; ++mt) {
#pragma unroll
            for (int r = 0; r < 4; ++r) {
                int m  = mt * 16 + q8 * 4 + r;
                int dn = dstS[m], sn = srcS[m];
                float d0 = d0S[m], d1 = d1S[m], d2 = d2S[m];
                float f1 = silu_f(acc[mt][nt2][r] + bf1);
                float f2 = silu_f(acc[mt][nt2 + 2][r] + bf2);
                size_t db = (size_t)dn * 384 + c1;
                size_t sb = (size_t)sn * 384 + c1;
                float a0 = vwt[db], a1 = vwt[db + HDIM], a2 = vwt[db + 2 * HDIM];
                float b0 = vws[sb], b1 = vws[sb + HDIM], b2 = vws[sb + 2 * HDIM];
                float t10 = vtt[db], t11 = vtt[db + HDIM], t12 = vtt[db + 2 * HDIM];
                float t20 = vts[db], t21 = vts[db + HDIM], t22 = vts[db + 2 * HDIM];
                float A  = a0 * d0 + a1 * d1 + a2 * d2;
                float B  = b0 * d0 + b1 * d1 + b2 * d2;
                float P1 = t10 * d0 + t11 * d1 + t12 * d2;
                float P2 = t20 * d0 + t21 * d1 + t22 * d2;
                float wdot = a0 * b0 + a1 * b1 + a2 * b2 - A * B;
                float tdot = t10 * t20 + t11 * t21 + t12 * t22 - P1 * P2;
                dfo[(size_t)(e0 + m) * HDIM + c1] = f1 * wdot + f2 * tdot;
            }
        }
    }

    // ================= P1: [dk|dv] GEMM =================
#pragma unroll
    for (int mt = 0; mt < 4; ++mt)
#pragma unroll
        for (int nt = 0; nt < 4; ++nt) acc[mt][nt] = v4f{0.f, 0.f, 0.f, 0.f};
    gemm_split(asH, asL, WmsgH, WmsgL, colbase, n16, q8, acc);

    // all waves done reading asH/asL (f_ij) before vj overwrites them
    __syncthreads();

    // ================= P2 + P3: attention, vj, xagg, vj->LDS split =================
#pragma unroll
    for (int nt2 = 0; nt2 < 2; ++nt2) {
        int c1 = colbase[nt2] + n16;
        float bdk1 = bdk[c1], bdv1 = bdv[c1];
#pragma unroll
        for (int mt = 0; mt < 4; ++mt) {
#pragma unroll
            for (int r = 0; r < 4; ++r) {
                int m  = mt * 16 + q8 * 4 + r;
                int dn = dstS[m], sn = srcS[m];
                float dk = silu_f(acc[mt][nt2][r] + bdk1);
                float p = q[(size_t)dn * HDIM + c1] * k[(size_t)sn * HDIM + c1] * dk;
                p += __shfl_xor(p, 1);
                p += __shfl_xor(p, 2);
                p += __shfl_xor(p, 4);
                p += __shfl_xor(p, 8);
                float at = silu_f(p) * rcutS[m];
                float dv = silu_f(acc[mt][nt2 + 2][r] + bdv1);
                float vjv = v[(size_t)sn * HDIM + c1] * dv * at;
                atomicAdd(&xagg[(size_t)dn * HDIM + c1], vjv);
                short h = f2bf(vjv);
                asH[m * 136 + c1] = h;
                asL[m * 136 + c1] = f2bf(vjv - bf2f(h));
            }
        }
    }
    __syncthreads();

    // ================= P4: [s1|s2] GEMM from vj =================
#pragma unroll
    for (int mt = 0; mt < 4; ++mt)
#pragma unroll
        for (int nt = 0; nt < 4; ++nt) acc[mt][nt] = v4f{0.f, 0.f, 0.f, 0.f};
    gemm_split(asH, asL, WstH, WstL, colbase, n16, q8, acc);

    // ================= P5: vec_msg scatter =================
#pragma unroll
    for (int nt2 = 0; nt2 < 2; ++nt2) {
        int c1 = colbase[nt2] + n16;
        float bs1 = bs[c1], bs2 = bs[HDIM + c1];
#pragma unroll
        for (int mt = 0; mt < 4; ++mt) {
#pragma unroll
            for (int r = 0; r < 4; ++r) {
                int m  = mt * 16 + q8 * 4 + r;
                int dn = dstS[m], sn = srcS[m];
                float d0 = d0S[m], d1 = d1S[m], d2 = d2S[m];
                float s1 = silu_f(acc[mt][nt2][r] + bs1);
                float s2 = silu_f(acc[mt][nt2 + 2][r] + bs2);
                size_t vb = (size_t)sn * 384 + c1;
                size_t ab = (size_t)dn * 384 + c1;
                atomicAdd(&dvec[ab],            fmaf(vec[vb],            s1, s2 * d0));
                atomicAdd(&dvec[ab + HDIM],     fmaf(vec[vb + HDIM],     s1, s2 * d1));
                atomicAdd(&dvec[ab + 2 * HDIM], fmaf(vec[vb + 2 * HDIM], s1, s2 * d2));
            }
        }
    }
}

// ---------------------------------------------------------------- node output: o=xagg@Wo+bo; dx, dvec+=vec3*o1
__global__ __launch_bounds__(256) void k_node_out(
    const float* __restrict__ xagg,
    const float* __restrict__ vecdot, const float* __restrict__ vec3o,
    const float* __restrict__ Wo, const float* __restrict__ bo,
    float* __restrict__ dx, float* __restrict__ dvec)
{
    __shared__ float xs[8 * HDIM];
    int base = blockIdx.x * 8;
    reinterpret_cast<float4*>(xs)[threadIdx.x] =
        reinterpret_cast<const float4*>(xagg + (size_t)base * HDIM)[threadIdx.x];
    __syncthreads();
    int h = threadIdx.x & 127, half = threadIdx.x >> 7;
    float o1[4], o2[4], o3[4];
#pragma unroll
    for (int i = 0; i < 4; ++i) { o1[i] = bo[h]; o2[i] = bo[HDIM + h]; o3[i] = bo[2 * HDIM + h]; }
    for (int kk = 0; kk < HDIM; ++kk) {
        float w1 = Wo[kk * 384 + h], w2 = Wo[kk * 384 + HDIM + h], w3 = Wo[kk * 384 + 2 * HDIM + h];
#pragma unroll
        for (int i = 0; i < 4; ++i) {
            float xv = xs[(half + 2 * i) * HDIM + kk];
            o1[i] = fmaf(xv, w1, o1[i]);
            o2[i] = fmaf(xv, w2, o2[i]);
            o3[i] = fmaf(xv, w3, o3[i]);
        }
    }
#pragma unroll
    for (int i = 0; i < 4; ++i) {
        int node = base + half + 2 * i;
        dx[(size_t)node * HDIM + h] = fmaf(vecdot[(size_t)node * HDIM + h], o2[i], o3[i]);
        size_t vb = (size_t)node * 3 * HDIM + h;
#pragma unroll
        for (int s = 0; s < 3; ++s)
            dvec[vb + s * HDIM] = fmaf(vec3o[vb + s * HDIM], o1[i], dvec[vb + s * HDIM]);
    }
}

// ----------------------------------------------------------------
extern "C" void kernel_launch(void* const* d_in, const int* in_sizes, int n_in,
                              void* d_out, int out_size, void* d_ws, size_t ws_size,
                              hipStream_t stream)
{
    const float* x     = (const float*)d_in[0];
    const float* vec   = (const float*)d_in[1];
    const int*   eidx  = (const int*)d_in[2];
    const float* rij   = (const float*)d_in[3];
    const float* fij   = (const float*)d_in[4];
    const float* dij   = (const float*)d_in[5];
    const float* Wq    = (const float*)d_in[6];
    const float* bq    = (const float*)d_in[7];
    const float* Wk    = (const float*)d_in[8];
    const float* bk    = (const float*)d_in[9];
    const float* Wv    = (const float*)d_in[10];
    const float* bv    = (const float*)d_in[11];
    const float* Wdk   = (const float*)d_in[12];
    const float* bdk   = (const float*)d_in[13];
    const float* Wdv   = (const float*)d_in[14];
    const float* bdv   = (const float*)d_in[15];
    const float* Wvec  = (const float*)d_in[16];
    const float* Ws    = (const float*)d_in[17];
    const float* bs    = (const float*)d_in[18];
    const float* Wo    = (const float*)d_in[19];
    const float* bo    = (const float*)d_in[20];
    const float* Wf    = (const float*)d_in[21];
    const float* bf    = (const float*)d_in[22];
    const float* Wwsrc = (const float*)d_in[23];
    const float* Wwtrg = (const float*)d_in[24];
    const float* Wtsrc = (const float*)d_in[25];
    const float* Wttrg = (const float*)d_in[26];

    float* ws = (float*)d_ws;
    size_t o = 0;
    float* q      = ws + o; o += (size_t)NATOM * HDIM;
    float* kf     = ws + o; o += (size_t)NATOM * HDIM;
    float* vf     = ws + o; o += (size_t)NATOM * HDIM;
    float* vecdot = ws + o; o += (size_t)NATOM * HDIM;
    float* vec3o  = ws + o; o += (size_t)NATOM * 3 * HDIM;
    float* vwt    = ws + o; o += (size_t)NATOM * 3 * HDIM;
    float* vws_   = ws + o; o += (size_t)NATOM * 3 * HDIM;
    float* vtt    = ws + o; o += (size_t)NATOM * 3 * HDIM;
    float* vts    = ws + o; o += (size_t)NATOM * 3 * HDIM;
    float* xagg   = ws + o; o += (size_t)NATOM * HDIM;
    // 6 bf16 weight buffers, each 256*128 shorts = 16384 floats
    short* WmsgH = (short*)(ws + o); o += 16384 / 2 * 1;  // keep float-based bookkeeping simple:
    // (each short buffer = 32768 shorts = 16384 floats)
    o -= 16384 / 2;  // undo; do explicit allocation below
    short* wbase = (short*)(ws + o);
    WmsgH = wbase + 0 * 32768;
    short* WmsgL = wbase + 1 * 32768;
    short* WstH  = wbase + 2 * 32768;
    short* WstL  = wbase + 3 * 32768;
    short* WftH  = wbase + 4 * 32768;
    short* WftL  = wbase + 5 * 32768;
    // total ws: ~102.8 MB

    float* dx   = (float*)d_out;
    float* dvec = dx + (size_t)NATOM * HDIM;        // also the vec_agg accumulator
    float* dfo  = dvec + (size_t)NATOM * 3 * HDIM;

    hipLaunchKernelGGL(k_prep, dim3(768), dim3(128), 0, stream,
                       Wdk, Wdv, Ws, Wf, WmsgH, WmsgL, WstH, WstL, WftH, WftL);
    hipLaunchKernelGGL(k_zero4, dim3((NATOM * HDIM / 4 + 255) / 256), dim3(256), 0, stream,
                       (float4*)xagg, NATOM * HDIM / 4);
    hipLaunchKernelGGL(k_zero4, dim3((NATOM * 3 * HDIM / 4 + 255) / 256), dim3(256), 0, stream,
                       (float4*)dvec, NATOM * 3 * HDIM / 4);
    hipLaunchKernelGGL(k_node_qkv, dim3(NATOM / 8), dim3(256), 0, stream,
                       x, Wq, bq, Wk, bk, Wv, bv, q, kf, vf);
    hipLaunchKernelGGL(k_node_vec, dim3(NATOM / 8), dim3(256), 0, stream,
                       vec, Wvec, Wwtrg, Wwsrc, Wttrg, Wtsrc,
                       vecdot, vec3o, vwt, vws_, vtt, vts);
    hipLaunchKernelGGL(k_edge_mega, dim3(NEDGE / 64), dim3(256), 0, stream,
                       fij, eidx, rij, dij, q, kf, vf, vec,
                       WmsgH, WmsgL, WstH, WstL, WftH, WftL,
                       bdk, bdv, bs, bf,
                       vwt, vws_, vtt, vts,
                       xagg, dvec, dfo);
    hipLaunchKernelGGL(k_node_out, dim3(NATOM / 8), dim3(256), 0, stream,
                       xagg, vecdot, vec3o, Wo, bo, dx, dvec);
}